// Round 3
// baseline (19.695 us; speedup 1.0000x reference)
//
#include <hip/hip_runtime.h>

// q[n] = v(n)^T M v(n), v = degree-2 Veronese of xh = [1, x0..x5].
// x layout: flat reshape of row-major (N,6) -> xv[d][n] = x_flat[d*N + n].
// M symmetric: fold q = sum_{j<=k} C_jk v_j v_k with C_jj = M_jj,
// C_jk = 2*M_jk (j<k), packed CONTIGUOUSLY (406 floats) in d_ws so the
// main kernel's wave-uniform coefficient reads become dense s_load_dwordx16
// batches instead of scattered row-segments with full lgkmcnt drains.

typedef float f32x2 __attribute__((ext_vector_type(2)));

__host__ __device__ constexpr int tri_off(int j) { return j * 28 - (j * (j - 1)) / 2; }

__global__ void pack_kernel(const float* __restrict__ M, float* __restrict__ C)
{
    int i = blockIdx.x * blockDim.x + threadIdx.x;
    if (i >= 406) return;
    int j = 0;
    while (tri_off(j + 1) <= i) ++j;          // row of triangle element i
    int k = j + (i - tri_off(j));             // column
    float m = M[j * 28 + k];
    C[i] = (k == j) ? m : 2.0f * m;
}

__global__ __launch_bounds__(256, 4)
void qform2_kernel(const float* __restrict__ x, const float* __restrict__ C,
                   float* __restrict__ out, int N2, int N)
{
    int t = blockIdx.x * blockDim.x + threadIdx.x;
    if (t >= N2) return;
    int n = 2 * t;

    f32x2 xh[7];
    xh[0] = (f32x2){1.0f, 1.0f};
    #pragma unroll
    for (int d = 0; d < 6; ++d)
        xh[d + 1] = *(const f32x2*)(x + (size_t)d * (size_t)N + n);

    // Veronese: combinations_with_replacement(range(7),2) order.
    f32x2 v[28];
    {
        int vi = 0;
        #pragma unroll
        for (int a = 0; a < 7; ++a)
            #pragma unroll
            for (int b = a; b < 7; ++b)
                v[vi++] = xh[a] * xh[b];
    }

    // q = sum_j v_j * (sum_{k>=j} C[tri(j,k)] * v_k); C is contiguous.
    f32x2 acc[4];
    #pragma unroll
    for (int i = 0; i < 4; ++i) acc[i] = (f32x2){0.0f, 0.0f};

    #pragma unroll
    for (int j = 0; j < 28; ++j) {
        float cjj = C[tri_off(j)];
        f32x2 tt = (f32x2){cjj, cjj} * v[j];            // diagonal term
        #pragma unroll
        for (int k = j + 1; k < 28; ++k) {
            float c = C[tri_off(j) + (k - j)];
            tt = __builtin_elementwise_fma((f32x2){c, c}, v[k], tt);
        }
        acc[j & 3] = __builtin_elementwise_fma(v[j], tt, acc[j & 3]);
    }
    f32x2 q = (acc[0] + acc[1]) + (acc[2] + acc[3]);
    *(f32x2*)(out + n) = q;
}

extern "C" void kernel_launch(void* const* d_in, const int* in_sizes, int n_in,
                              void* d_out, int out_size, void* d_ws, size_t ws_size,
                              hipStream_t stream)
{
    const float* x   = (const float*)d_in[0];   // 6*N floats
    const float* M   = (const float*)d_in[1];   // 28*28 floats
    float* out       = (float*)d_out;           // N floats
    float* C         = (float*)d_ws;            // 406 packed coeffs
    const int N      = out_size;                // 1,000,000 (even)
    const int N2     = N / 2;

    pack_kernel<<<1, 512, 0, stream>>>(M, C);

    const int block = 256;
    const int grid  = (N2 + block - 1) / block;
    qform2_kernel<<<grid, block, 0, stream>>>(x, C, out, N2, N);
}

// Round 4
// 14.565 us; speedup vs baseline: 1.3522x; 1.3522x over previous
//
#include <hip/hip_runtime.h>

// q[n] = v(n)^T M v(n), v = degree-2 Veronese of xh = [1, x0..x5].
// x layout: flat reshape of row-major (N,6) -> xv[d][n] = x_flat[d*N + n].
// M symmetric: q = sum_j Mjj vj^2 + 2 sum_{j<k} Mjk vj vk.
//
// Coefficient stream: inline-asm s_load_dwordx16 of M row-suffixes
// (row j: M[j][j..27], contiguous), software-pipelined one row ahead:
//   wait(row J) -> issue(row J+1) -> FMAs(row J).
// s_waitcnt is tied to the batch registers via "+s" (rule: compilers hoist
// consumers past standalone waitcnt asm); the issue-asm threads b0 through
// "+s" so the FMAs can't float above the prefetch.

typedef float f32x2  __attribute__((ext_vector_type(2)));
typedef float f32x16 __attribute__((ext_vector_type(16)));

// Byte offset of row J's diagonal element (M[J][J]) = 4*(29*J); row 27 is
// read back-aligned (last 16 floats of M, diag at element 15) to stay
// in-bounds. Second batch (rows 0..11 only) at +64 bytes.
#define ROW_OFF(J)  ((J) == 27 ? 3072 : 116 * (J))
#define ROW_OFF2(J) (116 * (J) + 64)

template <int J>
__device__ __forceinline__ void row_step(const float* __restrict__ M,
                                         const f32x2 (&v)[28],
                                         f32x2& qd, f32x2& qo,
                                         f32x16 b0, f32x16 b1)
{
    // Wait for row J's loads (issued one level up) — full drain (SMEM is
    // out-of-order, counted lgkmcnt is unsafe). Ties b0/b1 so uses order.
    if constexpr (J < 12)
        asm volatile("s_waitcnt lgkmcnt(0)" : "+s"(b0), "+s"(b1));
    else
        asm volatile("s_waitcnt lgkmcnt(0)" : "+s"(b0));

    // Issue row J+1 (prefetch). b0 threaded through so row-J FMAs stay below.
    f32x16 n0{}, n1{};
    if constexpr (J + 1 < 28) {
        asm volatile("s_load_dwordx16 %0, %2, %3"
                     : "=s"(n0), "+s"(b0)
                     : "s"(M), "i"(ROW_OFF(J + 1)));
        if constexpr (J + 1 < 12)
            asm volatile("s_load_dwordx16 %0, %2, %3"
                         : "=s"(n1), "+s"(b0)
                         : "s"(M), "i"(ROW_OFF2(J + 1)));
    }

    // Process row J.
    constexpr int d0 = (J == 27) ? 15 : 0;  // diag element index within b0
    {
        float c = b0[d0];
        qd = __builtin_elementwise_fma((f32x2){c, c}, v[J] * v[J], qd);
    }
    if constexpr (J < 27) {
        f32x2 t = (f32x2){0.0f, 0.0f};
        constexpr int n_in_b0 = (27 - J < 15) ? (27 - J) : 15;
        #pragma unroll
        for (int i = 1; i <= n_in_b0; ++i) {
            float c = b0[i];
            t = __builtin_elementwise_fma((f32x2){c, c}, v[J + i], t);
        }
        if constexpr (J < 12) {
            #pragma unroll
            for (int i = 0; i <= 11 - J; ++i) {
                float c = b1[i];
                t = __builtin_elementwise_fma((f32x2){c, c}, v[J + 16 + i], t);
            }
        }
        qo = __builtin_elementwise_fma(v[J], t, qo);
    }

    if constexpr (J + 1 < 28)
        row_step<J + 1>(M, v, qd, qo, n0, n1);
}

__global__ __launch_bounds__(256, 5)
void qform2_kernel(const float* __restrict__ x, const float* __restrict__ M,
                   float* __restrict__ out, int N2, int N)
{
    int t = blockIdx.x * blockDim.x + threadIdx.x;
    if (t >= N2) return;
    int n = 2 * t;

    f32x2 xh[7];
    xh[0] = (f32x2){1.0f, 1.0f};
    #pragma unroll
    for (int d = 0; d < 6; ++d)
        xh[d + 1] = *(const f32x2*)(x + (size_t)d * (size_t)N + n);

    // Veronese: combinations_with_replacement(range(7),2) order.
    f32x2 v[28];
    {
        int vi = 0;
        #pragma unroll
        for (int a = 0; a < 7; ++a)
            #pragma unroll
            for (int b = a; b < 7; ++b)
                v[vi++] = xh[a] * xh[b];
    }

    f32x2 qd = (f32x2){0.0f, 0.0f};
    f32x2 qo = (f32x2){0.0f, 0.0f};

    // Kick off row 0 (both batches), then run the pipelined triangle.
    f32x16 b0, b1;
    asm volatile("s_load_dwordx16 %0, %1, 0"  : "=s"(b0) : "s"(M));
    asm volatile("s_load_dwordx16 %0, %1, 64" : "=s"(b1) : "s"(M));
    row_step<0>(M, v, qd, qo, b0, b1);

    f32x2 q = __builtin_elementwise_fma((f32x2){2.0f, 2.0f}, qo, qd);
    *(f32x2*)(out + n) = q;
}

extern "C" void kernel_launch(void* const* d_in, const int* in_sizes, int n_in,
                              void* d_out, int out_size, void* d_ws, size_t ws_size,
                              hipStream_t stream)
{
    const float* x   = (const float*)d_in[0];   // 6*N floats
    const float* M   = (const float*)d_in[1];   // 28*28 floats
    float* out       = (float*)d_out;           // N floats
    const int N      = out_size;                // 1,000,000 (even)
    const int N2     = N / 2;

    const int block = 256;
    const int grid  = (N2 + block - 1) / block;
    qform2_kernel<<<grid, block, 0, stream>>>(x, M, out, N2, N);
}